// Round 1
// baseline (177.371 us; speedup 1.0000x reference)
//
#include <hip/hip_runtime.h>
#include <hip/hip_bf16.h>

// Flash-attention forward, causal, B=2 H=16 S=2048 D=64, fp32 in/out,
// bf16 MFMA compute (16x16x32), fp32 accumulation + online softmax.

#define S_LEN 2048
#define D_DIM 64
#define BQ 64
#define BKV 64
#define PAD 72   // padded LDS row length (bf16 elems); 144B row stride, 16B aligned

typedef __bf16 bf16x8 __attribute__((ext_vector_type(8)));
typedef float f32x4 __attribute__((ext_vector_type(4)));

__global__ __launch_bounds__(256)
void attn_fwd_kernel(const float* __restrict__ q, const float* __restrict__ k,
                     const float* __restrict__ v, float* __restrict__ out)
{
    __shared__ __bf16 Klds[BKV][PAD];      // K tile, row-major [k][d]
    __shared__ __bf16 Vt[D_DIM][PAD];      // V tile transposed [d][k]
    __shared__ __bf16 Plds[4][16][PAD];    // per-wave P buffer [wave][q_local][k]

    const int tid  = threadIdx.x;
    const int w    = tid >> 6;     // wave id 0..3
    const int lane = tid & 63;
    const int l15  = lane & 15;
    const int lg   = lane >> 4;    // lane group 0..3

    const int qtile = blockIdx.x;
    const int bh    = blockIdx.y;
    const int qbase = qtile * BQ;

    const size_t head_off = (size_t)bh * S_LEN * D_DIM;
    const float* qh = q + head_off;
    const float* kh = k + head_off;
    const float* vh = v + head_off;
    float*       oh = out + head_off;

    // ---- Q fragments (A operand): row = lane&15, k(d) = c*32 + 8*(lane>>4)+i
    // pre-scaled by 1/sqrt(D) = 0.125 (exact in bf16)
    bf16x8 qf[2];
    {
        const int qrow = qbase + w * 16 + l15;
        const float* qp = qh + (size_t)qrow * D_DIM + 8 * lg;
#pragma unroll
        for (int c = 0; c < 2; ++c) {
            float4 a = *(const float4*)(qp + c * 32);
            float4 b = *(const float4*)(qp + c * 32 + 4);
            bf16x8 f;
            f[0] = (__bf16)(a.x * 0.125f); f[1] = (__bf16)(a.y * 0.125f);
            f[2] = (__bf16)(a.z * 0.125f); f[3] = (__bf16)(a.w * 0.125f);
            f[4] = (__bf16)(b.x * 0.125f); f[5] = (__bf16)(b.y * 0.125f);
            f[6] = (__bf16)(b.z * 0.125f); f[7] = (__bf16)(b.w * 0.125f);
            qf[c] = f;
        }
    }

    f32x4 acc[4] = {};                 // O accumulator: 4 d-tiles of 16 cols
    float m_run[4], l_run[4];
#pragma unroll
    for (int r = 0; r < 4; ++r) { m_run[r] = -1e30f; l_run[r] = 0.0f; }

    const int nkv = qtile + 1;         // causal: only tiles with any j <= q
    for (int kt = 0; kt < nkv; ++kt) {
        const int kv0 = kt * BKV;

        __syncthreads();   // previous-tile LDS reads done before overwrite
        // ---- stage K tile and transposed V tile (fp32 -> bf16)
#pragma unroll
        for (int it = 0; it < 4; ++it) {
            int idx = tid + it * 256;         // 0..1023 over 64 rows x 16 float4
            int row = idx >> 4;
            int c4  = idx & 15;
            float4 kf = *(const float4*)(kh + (size_t)(kv0 + row) * D_DIM + c4 * 4);
            __bf16* kd = &Klds[row][c4 * 4];
            kd[0] = (__bf16)kf.x; kd[1] = (__bf16)kf.y;
            kd[2] = (__bf16)kf.z; kd[3] = (__bf16)kf.w;
            float4 vf = *(const float4*)(vh + (size_t)(kv0 + row) * D_DIM + c4 * 4);
            Vt[c4 * 4 + 0][row] = (__bf16)vf.x;
            Vt[c4 * 4 + 1][row] = (__bf16)vf.y;
            Vt[c4 * 4 + 2][row] = (__bf16)vf.z;
            Vt[c4 * 4 + 3][row] = (__bf16)vf.w;
        }
        __syncthreads();

        // ---- QK^T: S[q][j], C layout col=lane&15 (j), row=lg*4+r (q_local)
        f32x4 sfrag[4];
#pragma unroll
        for (int kc = 0; kc < 4; ++kc) {
            bf16x8 kf0 = *(const bf16x8*)&Klds[kc * 16 + l15][8 * lg];
            bf16x8 kf1 = *(const bf16x8*)&Klds[kc * 16 + l15][32 + 8 * lg];
            f32x4 c = {};
            c = __builtin_amdgcn_mfma_f32_16x16x32_bf16(qf[0], kf0, c, 0, 0, 0);
            c = __builtin_amdgcn_mfma_f32_16x16x32_bf16(qf[1], kf1, c, 0, 0, 0);
            sfrag[kc] = c;
        }

        // ---- causal mask: only the diagonal tile needs it
        if (kt == qtile) {
#pragma unroll
            for (int kc = 0; kc < 4; ++kc) {
                const int j = kv0 + kc * 16 + l15;
#pragma unroll
                for (int r = 0; r < 4; ++r) {
                    const int qrow = qbase + w * 16 + lg * 4 + r;
                    if (j > qrow) sfrag[kc][r] = -1e30f;
                }
            }
        }

        // ---- online softmax (per q-row; rows live in 16-lane groups)
        float mt[4], corr[4], ps[4];
#pragma unroll
        for (int r = 0; r < 4; ++r) {
            float mx = fmaxf(fmaxf(sfrag[0][r], sfrag[1][r]),
                             fmaxf(sfrag[2][r], sfrag[3][r]));
            mx = fmaxf(mx, __shfl_xor(mx, 1));
            mx = fmaxf(mx, __shfl_xor(mx, 2));
            mx = fmaxf(mx, __shfl_xor(mx, 4));
            mx = fmaxf(mx, __shfl_xor(mx, 8));
            mt[r]   = fmaxf(m_run[r], mx);
            corr[r] = __expf(m_run[r] - mt[r]);
            ps[r]   = 0.0f;
        }
#pragma unroll
        for (int kc = 0; kc < 4; ++kc) {
#pragma unroll
            for (int r = 0; r < 4; ++r) {
                float p = __expf(sfrag[kc][r] - mt[r]);
                ps[r] += p;
                Plds[w][lg * 4 + r][kc * 16 + l15] = (__bf16)p;
            }
        }
#pragma unroll
        for (int r = 0; r < 4; ++r) {
            ps[r] += __shfl_xor(ps[r], 1);
            ps[r] += __shfl_xor(ps[r], 2);
            ps[r] += __shfl_xor(ps[r], 4);
            ps[r] += __shfl_xor(ps[r], 8);
            l_run[r] = l_run[r] * corr[r] + ps[r];
            m_run[r] = mt[r];
        }
#pragma unroll
        for (int dt = 0; dt < 4; ++dt)
#pragma unroll
            for (int r = 0; r < 4; ++r)
                acc[dt][r] *= corr[r];

        // ---- PV: O[q][d] += P[q][k] * V[k][d]
        // A = P (row=lane&15=q_local, k=kk*32+8*lg+i)
        // B = Vt[d][k]: col=lane&15 -> d, k contiguous
#pragma unroll
        for (int kk = 0; kk < 2; ++kk) {
            bf16x8 pf = *(const bf16x8*)&Plds[w][l15][kk * 32 + 8 * lg];
#pragma unroll
            for (int dt = 0; dt < 4; ++dt) {
                bf16x8 vf = *(const bf16x8*)&Vt[dt * 16 + l15][kk * 32 + 8 * lg];
                acc[dt] = __builtin_amdgcn_mfma_f32_16x16x32_bf16(pf, vf, acc[dt], 0, 0, 0);
            }
        }
    }

    // ---- epilogue: O = acc / l, write fp32
#pragma unroll
    for (int dt = 0; dt < 4; ++dt) {
#pragma unroll
        for (int r = 0; r < 4; ++r) {
            const int qrow = qbase + w * 16 + lg * 4 + r;
            oh[(size_t)qrow * D_DIM + dt * 16 + l15] = acc[dt][r] / l_run[r];
        }
    }
}

extern "C" void kernel_launch(void* const* d_in, const int* in_sizes, int n_in,
                              void* d_out, int out_size, void* d_ws, size_t ws_size,
                              hipStream_t stream) {
    const float* q = (const float*)d_in[0];
    const float* k = (const float*)d_in[1];
    const float* v = (const float*)d_in[2];
    // d_in[3] = additive causal mask; implemented analytically, not read.
    float* out = (float*)d_out;

    dim3 grid(S_LEN / BQ, 2 * 16);  // 32 q-tiles x 32 heads
    dim3 block(256);
    attn_fwd_kernel<<<grid, block, 0, stream>>>(q, k, v, out);
}

// Round 2
// 88.997 us; speedup vs baseline: 1.9930x; 1.9930x over previous
//
#include <hip/hip_runtime.h>
#include <hip/hip_bf16.h>

// Flash-attention forward, causal, B=2 H=16 S=2048 D=64, fp32 in/out.
// Round 2: pre-convert K->bf16, V->V^T bf16 in d_ws; attention kernel uses
// global_load_lds staging with XOR-swizzled sources, swapped QK^T (mfma(K,Q))
// for in-register softmax (P never touches LDS), double-buffered LDS with
// raw s_barrier + manual vmcnt.

#define S_LEN 2048
#define D_DIM 64
#define BQ 64
#define BKV 64
#define NQT (S_LEN / BQ)
#define NBH 32

typedef __bf16 bf16x8 __attribute__((ext_vector_type(8)));
typedef __bf16 bf16x4 __attribute__((ext_vector_type(4)));
typedef float f32x4 __attribute__((ext_vector_type(4)));

#define QSCALE 0.1803368801111243f   // (1/8) * log2(e)
#define NEG_INF (-1e30f)

__device__ inline void glds16(const void* g, void* l) {
    __builtin_amdgcn_global_load_lds(
        (const __attribute__((address_space(1))) unsigned int*)g,
        (__attribute__((address_space(3))) unsigned int*)l, 16, 0, 0);
}

// ---------------- convert kernels ----------------

__global__ __launch_bounds__(256)
void conv_k_kernel(const float* __restrict__ k, __bf16* __restrict__ kb)
{
    size_t i = ((size_t)blockIdx.x * 256 + threadIdx.x) * 8;
    float4 a = *(const float4*)(k + i);
    float4 b = *(const float4*)(k + i + 4);
    bf16x8 o;
    o[0] = (__bf16)a.x; o[1] = (__bf16)a.y; o[2] = (__bf16)a.z; o[3] = (__bf16)a.w;
    o[4] = (__bf16)b.x; o[5] = (__bf16)b.y; o[6] = (__bf16)b.z; o[7] = (__bf16)b.w;
    *(bf16x8*)(kb + i) = o;
}

__global__ __launch_bounds__(256)
void conv_vt_kernel(const float* __restrict__ v, __bf16* __restrict__ vt)
{
    __shared__ __bf16 T[64][72];   // 144B row stride (8B-aligned rows)
    const int bh = blockIdx.y, st = blockIdx.x;
    const int tid = threadIdx.x;
    const float* vh = v + (size_t)bh * S_LEN * D_DIM + (size_t)st * 64 * D_DIM;
#pragma unroll
    for (int it = 0; it < 4; ++it) {
        int idx = tid + it * 256;          // 64 s-rows x 16 float4
        int s = idx >> 4, c4 = idx & 15;
        float4 f = *(const float4*)(vh + s * D_DIM + c4 * 4);
        T[c4 * 4 + 0][s] = (__bf16)f.x;
        T[c4 * 4 + 1][s] = (__bf16)f.y;
        T[c4 * 4 + 2][s] = (__bf16)f.z;
        T[c4 * 4 + 3][s] = (__bf16)f.w;
    }
    __syncthreads();
    __bf16* vth = vt + (size_t)bh * D_DIM * S_LEN + st * 64;
#pragma unroll
    for (int it = 0; it < 2; ++it) {
        int idx = tid + it * 256;          // 64 d-rows x 8 chunks of 8
        int d = idx >> 3, c8 = idx & 7;
        bf16x4 v0 = *(const bf16x4*)&T[d][c8 * 8];
        bf16x4 v1 = *(const bf16x4*)&T[d][c8 * 8 + 4];
        bf16x8 o;
        o[0] = v0[0]; o[1] = v0[1]; o[2] = v0[2]; o[3] = v0[3];
        o[4] = v1[0]; o[5] = v1[1]; o[6] = v1[2]; o[7] = v1[3];
        *(bf16x8*)(vth + (size_t)d * S_LEN + c8 * 8) = o;
    }
}

// ---------------- attention kernel (glds path) ----------------

__global__ __launch_bounds__(256)
void attn_fwd_glds(const float* __restrict__ q, const __bf16* __restrict__ kb,
                   const __bf16* __restrict__ vt, float* __restrict__ out)
{
    __shared__ __bf16 KL[2][64][64];   // [buf][j][d], cols XOR-swizzled by ((j&7)<<3)
    __shared__ __bf16 VL[2][64][64];   // [buf][d][j], cols XOR-swizzled by ((d&7)<<3)

    const int tid  = threadIdx.x;
    const int w    = tid >> 6;
    const int lane = tid & 63;
    const int l15  = lane & 15;
    const int lg   = lane >> 4;

    const int qtile = (int)gridDim.x - 1 - (int)blockIdx.x;  // longest blocks first
    const int bh    = blockIdx.y;
    const int qbase = qtile * BQ;

    const float*  qh = q  + (size_t)bh * S_LEN * D_DIM;
    const __bf16* kh = kb + (size_t)bh * S_LEN * D_DIM;
    const __bf16* vh = vt + (size_t)bh * D_DIM * S_LEN;
    float*        oh = out + (size_t)bh * S_LEN * D_DIM;

    // Q fragment (B operand): l15 = q row, elems d = kk*32 + 8*lg + i.
    // Pre-scaled by (1/sqrt(D)) * log2(e) so softmax uses exp2.
    bf16x8 qf[2];
    {
        const int qrow = qbase + w * 16 + l15;
        const float* qp = qh + (size_t)qrow * D_DIM + 8 * lg;
#pragma unroll
        for (int kk = 0; kk < 2; ++kk) {
            float4 a = *(const float4*)(qp + kk * 32);
            float4 b = *(const float4*)(qp + kk * 32 + 4);
            bf16x8 f;
            f[0] = (__bf16)(a.x * QSCALE); f[1] = (__bf16)(a.y * QSCALE);
            f[2] = (__bf16)(a.z * QSCALE); f[3] = (__bf16)(a.w * QSCALE);
            f[4] = (__bf16)(b.x * QSCALE); f[5] = (__bf16)(b.y * QSCALE);
            f[6] = (__bf16)(b.z * QSCALE); f[7] = (__bf16)(b.w * QSCALE);
            qf[kk] = f;
        }
    }

    // Staging decode: chunk c = u*4 + w; LDS elems e = c*512 + lane*8;
    // tile row r = e>>6, col0 = e&63 (multiple of 8). Source column is
    // XOR-swizzled so linear LDS holds the swizzled layout.
    int row_u[2], scol_u[2];
#pragma unroll
    for (int u = 0; u < 2; ++u) {
        int e = (u * 4 + w) * 512 + lane * 8;
        int r = e >> 6, c0 = e & 63;
        row_u[u]  = r;
        scol_u[u] = c0 ^ ((r & 7) << 3);
    }

#define STAGE(kt, buf)                                                          \
    {                                                                           \
        _Pragma("unroll")                                                       \
        for (int u = 0; u < 2; ++u) {                                           \
            glds16(kh + (size_t)((kt) * BKV + row_u[u]) * D_DIM + scol_u[u],    \
                   (__bf16*)&KL[buf][0][0] + (u * 4 + w) * 512);                \
            glds16(vh + (size_t)row_u[u] * S_LEN + (kt) * BKV + scol_u[u],      \
                   (__bf16*)&VL[buf][0][0] + (u * 4 + w) * 512);                \
        }                                                                       \
    }

    f32x4 acc[4] = {};
    float m_run = NEG_INF, l_run = 0.0f;   // lane owns q-row = l15 (x4 copies)

    STAGE(0, 0);

    for (int kt = 0; kt <= qtile; ++kt) {
        const int cur = kt & 1;
        asm volatile("s_waitcnt vmcnt(0)" ::: "memory");
        __builtin_amdgcn_s_barrier();
        if (kt < qtile) STAGE(kt + 1, cur ^ 1);

        // ---- swapped QK^T: s = mfma(K, Q) -> lane holds S[j][q=l15],
        //      j = jt*16 + 4*lg + r
        f32x4 s[4];
#pragma unroll
        for (int jt = 0; jt < 4; ++jt) {
            const int j  = jt * 16 + l15;
            const int sw = (j & 7) << 3;
            f32x4 c = {};
#pragma unroll
            for (int kk = 0; kk < 2; ++kk) {
                bf16x8 kf = *(const bf16x8*)&KL[cur][j][(kk * 32 + 8 * lg) ^ sw];
                c = __builtin_amdgcn_mfma_f32_16x16x32_bf16(kf, qf[kk], c, 0, 0, 0);
            }
            s[jt] = c;
        }

        // ---- causal mask: diagonal tile only
        if (kt == qtile) {
            const int qin = w * 16 + l15;
#pragma unroll
            for (int jt = 0; jt < 4; ++jt)
#pragma unroll
                for (int r = 0; r < 4; ++r)
                    if (jt * 16 + 4 * lg + r > qin) s[jt][r] = NEG_INF;
        }

        // ---- online softmax, fully in-register (log2 domain)
        float mx = NEG_INF;
#pragma unroll
        for (int jt = 0; jt < 4; ++jt)
#pragma unroll
            for (int r = 0; r < 4; ++r) mx = fmaxf(mx, s[jt][r]);
        mx = fmaxf(mx, __shfl_xor(mx, 16));
        mx = fmaxf(mx, __shfl_xor(mx, 32));
        const float mt   = fmaxf(m_run, mx);
        const float corr = __builtin_amdgcn_exp2f(m_run - mt);

        float p[4][4];
        float ps = 0.0f;
#pragma unroll
        for (int jt = 0; jt < 4; ++jt)
#pragma unroll
            for (int r = 0; r < 4; ++r) {
                float e = __builtin_amdgcn_exp2f(s[jt][r] - mt);
                p[jt][r] = e;
                ps += e;
            }
        ps += __shfl_xor(ps, 16);
        ps += __shfl_xor(ps, 32);
        l_run = l_run * corr + ps;
        m_run = mt;

        // corr redistribution: acc rows are q' = 4*lg + r; copies live in lanes l15=q'
        float corr_a[4];
#pragma unroll
        for (int r = 0; r < 4; ++r) corr_a[r] = __shfl(corr, 4 * lg + r);
#pragma unroll
        for (int dt = 0; dt < 4; ++dt)
#pragma unroll
            for (int r = 0; r < 4; ++r) acc[dt][r] *= corr_a[r];

        // ---- P -> bf16 A-fragments, j-order: {kk*32+4lg+i, kk*32+16+4lg+i}
        bf16x8 pa[2];
#pragma unroll
        for (int kk = 0; kk < 2; ++kk) {
#pragma unroll
            for (int i = 0; i < 4; ++i) {
                pa[kk][i]     = (__bf16)p[2 * kk][i];
                pa[kk][4 + i] = (__bf16)p[2 * kk + 1][i];
            }
        }

        // ---- PV: acc[dt] += P * V, B from swizzled V^T LDS in matching j-order
#pragma unroll
        for (int dt = 0; dt < 4; ++dt) {
            const int d  = dt * 16 + l15;
            const int sw = (d & 7) << 3;
#pragma unroll
            for (int kk = 0; kk < 2; ++kk) {
                bf16x4 v0 = *(const bf16x4*)&VL[cur][d][(kk * 32 + 4 * lg) ^ sw];
                bf16x4 v1 = *(const bf16x4*)&VL[cur][d][(kk * 32 + 16 + 4 * lg) ^ sw];
                bf16x8 vb;
                vb[0] = v0[0]; vb[1] = v0[1]; vb[2] = v0[2]; vb[3] = v0[3];
                vb[4] = v1[0]; vb[5] = v1[1]; vb[6] = v1[2]; vb[7] = v1[3];
                acc[dt] = __builtin_amdgcn_mfma_f32_16x16x32_bf16(pa[kk], vb, acc[dt], 0, 0, 0);
            }
        }
    }

    // ---- epilogue: rows q' = 4*lg + r, cols d = dt*16 + l15
    float l_a[4];
#pragma unroll
    for (int r = 0; r < 4; ++r) l_a[r] = __shfl(l_run, 4 * lg + r);
#pragma unroll
    for (int dt = 0; dt < 4; ++dt)
#pragma unroll
        for (int r = 0; r < 4; ++r)
            oh[(size_t)(qbase + w * 16 + 4 * lg + r) * D_DIM + dt * 16 + l15] =
                acc[dt][r] / l_a[r];
#undef STAGE
}

// ---------------- fallback (round-1 kernel, used only if ws too small) ----------------

#define PAD 72
__global__ __launch_bounds__(256)
void attn_fwd_fallback(const float* __restrict__ q, const float* __restrict__ k,
                       const float* __restrict__ v, float* __restrict__ out)
{
    __shared__ __bf16 Klds[BKV][PAD];
    __shared__ __bf16 Vt[D_DIM][PAD];
    __shared__ __bf16 Plds[4][16][PAD];

    const int tid  = threadIdx.x;
    const int w    = tid >> 6;
    const int lane = tid & 63;
    const int l15  = lane & 15;
    const int lg   = lane >> 4;

    const int qtile = blockIdx.x;
    const int bh    = blockIdx.y;
    const int qbase = qtile * BQ;

    const size_t head_off = (size_t)bh * S_LEN * D_DIM;
    const float* qh = q + head_off;
    const float* kh = k + head_off;
    const float* vh = v + head_off;
    float*       oh = out + head_off;

    bf16x8 qf[2];
    {
        const int qrow = qbase + w * 16 + l15;
        const float* qp = qh + (size_t)qrow * D_DIM + 8 * lg;
#pragma unroll
        for (int c = 0; c < 2; ++c) {
            float4 a = *(const float4*)(qp + c * 32);
            float4 b = *(const float4*)(qp + c * 32 + 4);
            bf16x8 f;
            f[0] = (__bf16)(a.x * 0.125f); f[1] = (__bf16)(a.y * 0.125f);
            f[2] = (__bf16)(a.z * 0.125f); f[3] = (__bf16)(a.w * 0.125f);
            f[4] = (__bf16)(b.x * 0.125f); f[5] = (__bf16)(b.y * 0.125f);
            f[6] = (__bf16)(b.z * 0.125f); f[7] = (__bf16)(b.w * 0.125f);
            qf[c] = f;
        }
    }

    f32x4 acc[4] = {};
    float m_run[4], l_run[4];
#pragma unroll
    for (int r = 0; r < 4; ++r) { m_run[r] = -1e30f; l_run[r] = 0.0f; }

    const int nkv = qtile + 1;
    for (int kt = 0; kt < nkv; ++kt) {
        const int kv0 = kt * BKV;
        __syncthreads();
#pragma unroll
        for (int it = 0; it < 4; ++it) {
            int idx = tid + it * 256;
            int row = idx >> 4;
            int c4  = idx & 15;
            float4 kf = *(const float4*)(kh + (size_t)(kv0 + row) * D_DIM + c4 * 4);
            __bf16* kd = &Klds[row][c4 * 4];
            kd[0] = (__bf16)kf.x; kd[1] = (__bf16)kf.y;
            kd[2] = (__bf16)kf.z; kd[3] = (__bf16)kf.w;
            float4 vf = *(const float4*)(vh + (size_t)(kv0 + row) * D_DIM + c4 * 4);
            Vt[c4 * 4 + 0][row] = (__bf16)vf.x;
            Vt[c4 * 4 + 1][row] = (__bf16)vf.y;
            Vt[c4 * 4 + 2][row] = (__bf16)vf.z;
            Vt[c4 * 4 + 3][row] = (__bf16)vf.w;
        }
        __syncthreads();

        f32x4 sfrag[4];
#pragma unroll
        for (int kc = 0; kc < 4; ++kc) {
            bf16x8 kf0 = *(const bf16x8*)&Klds[kc * 16 + l15][8 * lg];
            bf16x8 kf1 = *(const bf16x8*)&Klds[kc * 16 + l15][32 + 8 * lg];
            f32x4 c = {};
            c = __builtin_amdgcn_mfma_f32_16x16x32_bf16(qf[0], kf0, c, 0, 0, 0);
            c = __builtin_amdgcn_mfma_f32_16x16x32_bf16(qf[1], kf1, c, 0, 0, 0);
            sfrag[kc] = c;
        }

        if (kt == qtile) {
#pragma unroll
            for (int kc = 0; kc < 4; ++kc) {
                const int j = kv0 + kc * 16 + l15;
#pragma unroll
                for (int r = 0; r < 4; ++r) {
                    const int qrow = qbase + w * 16 + lg * 4 + r;
                    if (j > qrow) sfrag[kc][r] = -1e30f;
                }
            }
        }

        float mt[4], corr[4], ps[4];
#pragma unroll
        for (int r = 0; r < 4; ++r) {
            float mx = fmaxf(fmaxf(sfrag[0][r], sfrag[1][r]),
                             fmaxf(sfrag[2][r], sfrag[3][r]));
            mx = fmaxf(mx, __shfl_xor(mx, 1));
            mx = fmaxf(mx, __shfl_xor(mx, 2));
            mx = fmaxf(mx, __shfl_xor(mx, 4));
            mx = fmaxf(mx, __shfl_xor(mx, 8));
            mt[r]   = fmaxf(m_run[r], mx);
            corr[r] = __expf(m_run[r] - mt[r]);
            ps[r]   = 0.0f;
        }
#pragma unroll
        for (int kc = 0; kc < 4; ++kc) {
#pragma unroll
            for (int r = 0; r < 4; ++r) {
                float pp = __expf(sfrag[kc][r] - mt[r]);
                ps[r] += pp;
                Plds[w][lg * 4 + r][kc * 16 + l15] = (__bf16)pp;
            }
        }
#pragma unroll
        for (int r = 0; r < 4; ++r) {
            ps[r] += __shfl_xor(ps[r], 1);
            ps[r] += __shfl_xor(ps[r], 2);
            ps[r] += __shfl_xor(ps[r], 4);
            ps[r] += __shfl_xor(ps[r], 8);
            l_run[r] = l_run[r] * corr[r] + ps[r];
            m_run[r] = mt[r];
        }
#pragma unroll
        for (int dt = 0; dt < 4; ++dt)
#pragma unroll
            for (int r = 0; r < 4; ++r)
                acc[dt][r] *= corr[r];

#pragma unroll
        for (int kk = 0; kk < 2; ++kk) {
            bf16x8 pf = *(const bf16x8*)&Plds[w][l15][kk * 32 + 8 * lg];
#pragma unroll
            for (int dt = 0; dt < 4; ++dt) {
                bf16x8 vf = *(const bf16x8*)&Vt[dt * 16 + l15][kk * 32 + 8 * lg];
                acc[dt] = __builtin_amdgcn_mfma_f32_16x16x32_bf16(pf, vf, acc[dt], 0, 0, 0);
            }
        }
    }

#pragma unroll
    for (int dt = 0; dt < 4; ++dt) {
#pragma unroll
        for (int r = 0; r < 4; ++r) {
            const int qrow = qbase + w * 16 + lg * 4 + r;
            oh[(size_t)qrow * D_DIM + dt * 16 + l15] = acc[dt][r] / l_run[r];
        }
    }
}

extern "C" void kernel_launch(void* const* d_in, const int* in_sizes, int n_in,
                              void* d_out, int out_size, void* d_ws, size_t ws_size,
                              hipStream_t stream) {
    const float* q = (const float*)d_in[0];
    const float* k = (const float*)d_in[1];
    const float* v = (const float*)d_in[2];
    float* out = (float*)d_out;

    const size_t kv_elems  = (size_t)NBH * S_LEN * D_DIM;       // 4,194,304
    const size_t ws_needed = kv_elems * 2 * sizeof(__bf16);     // 16 MiB

    if (ws_size >= ws_needed) {
        __bf16* kb = (__bf16*)d_ws;
        __bf16* vt = kb + kv_elems;
        conv_k_kernel<<<dim3(kv_elems / (256 * 8)), dim3(256), 0, stream>>>(k, kb);
        conv_vt_kernel<<<dim3(S_LEN / 64, NBH), dim3(256), 0, stream>>>(v, vt);
        attn_fwd_glds<<<dim3(NQT, NBH), dim3(256), 0, stream>>>(q, kb, vt, out);
    } else {
        attn_fwd_fallback<<<dim3(NQT, NBH), dim3(256), 0, stream>>>(q, k, v, out);
    }
}

// Round 3
// 64.582 us; speedup vs baseline: 2.7464x; 1.3781x over previous
//
#include <hip/hip_runtime.h>
#include <hip/hip_bf16.h>

// Flash-attention forward, causal, B=2 H=16 S=2048 D=64, fp32 in/out.
// Round 3: causal pairing (block does qtiles {31-p, p} -> uniform 33 tile-units),
// 3-buffer LDS pipeline with counted vmcnt(4), defer-max softmax, permuted V^T
// columns so PV B-fragment is a single ds_read_b128, setprio around MFMA.

#define S_LEN 2048
#define D_DIM 64
#define BQ 64
#define BKV 64
#define NQT (S_LEN / BQ)
#define NBH 32

typedef __bf16 bf16x8 __attribute__((ext_vector_type(8)));
typedef __bf16 bf16x4 __attribute__((ext_vector_type(4)));
typedef float f32x4 __attribute__((ext_vector_type(4)));

#define QSCALE 0.1803368801111243f   // (1/8) * log2(e)
#define NEG_INF (-1e30f)
#define THRLOG2 11.5f                // defer-max threshold (log2 domain) ~ e^8

__device__ inline void glds16(const void* g, void* l) {
    __builtin_amdgcn_global_load_lds(
        (const __attribute__((address_space(1))) unsigned int*)g,
        (__attribute__((address_space(3))) unsigned int*)l, 16, 0, 0);
}

__device__ inline float m3(float a, float b, float c) {
    return fmaxf(fmaxf(a, b), c);    // clang fuses to v_max3_f32
}

// ---------------- convert kernels ----------------

__global__ __launch_bounds__(256)
void conv_k_kernel(const float* __restrict__ k, __bf16* __restrict__ kb)
{
    size_t i = ((size_t)blockIdx.x * 256 + threadIdx.x) * 8;
    float4 a = *(const float4*)(k + i);
    float4 b = *(const float4*)(k + i + 4);
    bf16x8 o;
    o[0] = (__bf16)a.x; o[1] = (__bf16)a.y; o[2] = (__bf16)a.z; o[3] = (__bf16)a.w;
    o[4] = (__bf16)b.x; o[5] = (__bf16)b.y; o[6] = (__bf16)b.z; o[7] = (__bf16)b.w;
    *(bf16x8*)(kb + i) = o;
}

// V^T with per-64-block column permutation: within each 64-col block,
// dest col c = (kk<<5)|(g<<3)|(b<<2)|i0  holds source j = (kk<<5)|(b<<4)|(g<<2)|i0.
// This makes the PV B-fragment (j-order kk*32 + 16b + 4g + i0) contiguous.
__global__ __launch_bounds__(256)
void conv_vt_kernel(const float* __restrict__ v, __bf16* __restrict__ vt)
{
    __shared__ __bf16 T[64][72];
    const int bh = blockIdx.y, st = blockIdx.x;
    const int tid = threadIdx.x;
    const float* vh = v + (size_t)bh * S_LEN * D_DIM + (size_t)st * 64 * D_DIM;
#pragma unroll
    for (int it = 0; it < 4; ++it) {
        int idx = tid + it * 256;          // 64 s-rows x 16 float4
        int s = idx >> 4, c4 = idx & 15;
        float4 f = *(const float4*)(vh + s * D_DIM + c4 * 4);
        T[c4 * 4 + 0][s] = (__bf16)f.x;
        T[c4 * 4 + 1][s] = (__bf16)f.y;
        T[c4 * 4 + 2][s] = (__bf16)f.z;
        T[c4 * 4 + 3][s] = (__bf16)f.w;
    }
    __syncthreads();
    __bf16* vth = vt + (size_t)bh * D_DIM * S_LEN + st * 64;
#pragma unroll
    for (int it = 0; it < 2; ++it) {
        int idx = tid + it * 256;          // 64 d-rows x 8 chunks of 8
        int d = idx >> 3, c8 = idx & 7;
        int kk = c8 >> 2, g = c8 & 3;
        bf16x4 v0 = *(const bf16x4*)&T[d][kk * 32 + 4 * g];        // b=0
        bf16x4 v1 = *(const bf16x4*)&T[d][kk * 32 + 16 + 4 * g];   // b=1
        bf16x8 o;
        o[0] = v0[0]; o[1] = v0[1]; o[2] = v0[2]; o[3] = v0[3];
        o[4] = v1[0]; o[5] = v1[1]; o[6] = v1[2]; o[7] = v1[3];
        *(bf16x8*)(vth + (size_t)d * S_LEN + c8 * 8) = o;
    }
}

// ---------------- attention kernel ----------------

__global__ __launch_bounds__(256)
void attn_fwd_glds(const float* __restrict__ q, const __bf16* __restrict__ kb,
                   const __bf16* __restrict__ vt, float* __restrict__ out)
{
    __shared__ __bf16 KL[3][64][64];   // [buf][j][d], cols XOR-swizzled by ((j&7)<<3)
    __shared__ __bf16 VL[3][64][64];   // [buf][d][c], permuted cols, XOR-swizzled by ((d&7)<<3)

    const int tid  = threadIdx.x;
    const int w    = tid >> 6;
    const int lane = tid & 63;
    const int l15  = lane & 15;
    const int lg   = lane >> 4;

    const int p  = blockIdx.x;         // pair index 0..15
    const int bh = blockIdx.y;

    const float*  qh = q  + (size_t)bh * S_LEN * D_DIM;
    const __bf16* kh = kb + (size_t)bh * S_LEN * D_DIM;
    const __bf16* vh = vt + (size_t)bh * D_DIM * S_LEN;
    float*        oh = out + (size_t)bh * S_LEN * D_DIM;

    // staging decode (chunk c = u*4 + w; LDS elems e = c*512 + lane*8)
    int row_u[2], scol_u[2];
#pragma unroll
    for (int u = 0; u < 2; ++u) {
        int e = (u * 4 + w) * 512 + lane * 8;
        int r = e >> 6, c0 = e & 63;
        row_u[u]  = r;
        scol_u[u] = c0 ^ ((r & 7) << 3);
    }

#define STAGE(kt, buf)                                                          \
    {                                                                           \
        _Pragma("unroll")                                                       \
        for (int u = 0; u < 2; ++u) {                                           \
            glds16(kh + (size_t)((kt) * BKV + row_u[u]) * D_DIM + scol_u[u],    \
                   (__bf16*)&KL[buf][0][0] + (u * 4 + w) * 512);                \
            glds16(vh + (size_t)row_u[u] * S_LEN + (kt) * BKV + scol_u[u],      \
                   (__bf16*)&VL[buf][0][0] + (u * 4 + w) * 512);                \
        }                                                                       \
    }

    for (int half = 0; half < 2; ++half) {
        const int qtile = (half == 0) ? (NQT - 1 - p) : p;   // big half first
        const int qbase = qtile * BQ;
        const int nt    = qtile + 1;

        // ---- Q fragment (B operand): l15 = q row, elems d = kk*32 + 8*lg + i
        bf16x8 qf[2];
        {
            const int qrow = qbase + w * 16 + l15;
            const float* qp = qh + (size_t)qrow * D_DIM + 8 * lg;
#pragma unroll
            for (int kk = 0; kk < 2; ++kk) {
                float4 a = *(const float4*)(qp + kk * 32);
                float4 b = *(const float4*)(qp + kk * 32 + 4);
                bf16x8 f;
                f[0] = (__bf16)(a.x * QSCALE); f[1] = (__bf16)(a.y * QSCALE);
                f[2] = (__bf16)(a.z * QSCALE); f[3] = (__bf16)(a.w * QSCALE);
                f[4] = (__bf16)(b.x * QSCALE); f[5] = (__bf16)(b.y * QSCALE);
                f[6] = (__bf16)(b.z * QSCALE); f[7] = (__bf16)(b.w * QSCALE);
                qf[kk] = f;
            }
        }

        f32x4 acc[4] = {};
        float m_run = NEG_INF, l_run = 0.0f;

        if (half == 1) __syncthreads();   // protect LDS reuse across halves
        STAGE(0, 0);
        if (nt > 1) STAGE(1, 1);

        for (int kt = 0; kt < nt; ++kt) {
            const int cur = kt % 3;
            if (kt + 1 < nt) { asm volatile("s_waitcnt vmcnt(4)" ::: "memory"); }
            else             { asm volatile("s_waitcnt vmcnt(0)" ::: "memory"); }
            __builtin_amdgcn_s_barrier();
            if (kt + 2 < nt) STAGE(kt + 2, (kt + 2) % 3);

            // ---- swapped QK^T: s = mfma(K, Q); lane holds S[j][q=l15], j = jt*16+4lg+r
            f32x4 s[4];
            __builtin_amdgcn_s_setprio(1);
#pragma unroll
            for (int jt = 0; jt < 4; ++jt) {
                const int j  = jt * 16 + l15;
                const int sw = (j & 7) << 3;
                f32x4 c = {};
#pragma unroll
                for (int kk = 0; kk < 2; ++kk) {
                    bf16x8 kf = *(const bf16x8*)&KL[cur][j][(kk * 32 + 8 * lg) ^ sw];
                    c = __builtin_amdgcn_mfma_f32_16x16x32_bf16(kf, qf[kk], c, 0, 0, 0);
                }
                s[jt] = c;
            }
            __builtin_amdgcn_s_setprio(0);

            // ---- causal mask on diagonal tile
            if (kt == qtile) {
                const int qin = w * 16 + l15;
#pragma unroll
                for (int jt = 0; jt < 4; ++jt)
#pragma unroll
                    for (int r = 0; r < 4; ++r)
                        if (jt * 16 + 4 * lg + r > qin) s[jt][r] = NEG_INF;
            }

            // ---- row max (max3 trees + 2 shfl)
            float t0 = m3(s[0][0], s[0][1], s[0][2]);
            float t1 = m3(s[0][3], s[1][0], s[1][1]);
            float t2 = m3(s[1][2], s[1][3], s[2][0]);
            float t3 = m3(s[2][1], s[2][2], s[2][3]);
            float t4 = m3(s[3][0], s[3][1], s[3][2]);
            float mx = m3(m3(t0, t1, t2), m3(t3, t4, s[3][3]), NEG_INF);
            mx = fmaxf(mx, __shfl_xor(mx, 16));
            mx = fmaxf(mx, __shfl_xor(mx, 32));

            // ---- defer-max: rescale only when the running max grew materially
            if (__any(mx > m_run + THRLOG2)) {
                const float mt   = fmaxf(m_run, mx);
                const float corr = __builtin_amdgcn_exp2f(m_run - mt);
                l_run *= corr;
                m_run  = mt;
                float corr_a[4];
#pragma unroll
                for (int r = 0; r < 4; ++r) corr_a[r] = __shfl(corr, 4 * lg + r);
#pragma unroll
                for (int dt = 0; dt < 4; ++dt)
#pragma unroll
                    for (int r = 0; r < 4; ++r) acc[dt][r] *= corr_a[r];
            }

            // ---- P = exp2(s - m), row-sum, bf16 A-fragments
            float ps = 0.0f;
            float pe[4][4];
#pragma unroll
            for (int jt = 0; jt < 4; ++jt)
#pragma unroll
                for (int r = 0; r < 4; ++r) {
                    float e = __builtin_amdgcn_exp2f(s[jt][r] - m_run);
                    pe[jt][r] = e;
                    ps += e;
                }
            ps += __shfl_xor(ps, 16);
            ps += __shfl_xor(ps, 32);
            l_run += ps;

            bf16x8 pa[2];
#pragma unroll
            for (int kk = 0; kk < 2; ++kk)
#pragma unroll
                for (int i = 0; i < 4; ++i) {
                    pa[kk][i]     = (__bf16)pe[2 * kk][i];
                    pa[kk][4 + i] = (__bf16)pe[2 * kk + 1][i];
                }

            // ---- PV: single b128 B-fragment thanks to permuted V^T columns
            __builtin_amdgcn_s_setprio(1);
#pragma unroll
            for (int dt = 0; dt < 4; ++dt) {
                const int d  = dt * 16 + l15;
                const int sw = (d & 7) << 3;
#pragma unroll
                for (int kk = 0; kk < 2; ++kk) {
                    bf16x8 vb = *(const bf16x8*)&VL[cur][d][(kk * 32 + 8 * lg) ^ sw];
                    acc[dt] = __builtin_amdgcn_mfma_f32_16x16x32_bf16(pa[kk], vb, acc[dt], 0, 0, 0);
                }
            }
            __builtin_amdgcn_s_setprio(0);
        }

        // ---- epilogue: rows q' = 4*lg + r, cols d = dt*16 + l15
        float l_a[4];
#pragma unroll
        for (int r = 0; r < 4; ++r) l_a[r] = __shfl(l_run, 4 * lg + r);
#pragma unroll
        for (int dt = 0; dt < 4; ++dt)
#pragma unroll
            for (int r = 0; r < 4; ++r)
                oh[(size_t)(qbase + w * 16 + 4 * lg + r) * D_DIM + dt * 16 + l15] =
                    acc[dt][r] / l_a[r];
    }
#undef STAGE
}

// ---------------- fallback (no-ws path) ----------------

#define PAD 72
__global__ __launch_bounds__(256)
void attn_fwd_fallback(const float* __restrict__ q, const float* __restrict__ k,
                       const float* __restrict__ v, float* __restrict__ out)
{
    __shared__ __bf16 Klds[BKV][PAD];
    __shared__ __bf16 Vt[D_DIM][PAD];
    __shared__ __bf16 Plds[4][16][PAD];

    const int tid  = threadIdx.x;
    const int w    = tid >> 6;
    const int lane = tid & 63;
    const int l15  = lane & 15;
    const int lg   = lane >> 4;

    const int qtile = blockIdx.x;
    const int bh    = blockIdx.y;
    const int qbase = qtile * BQ;

    const size_t head_off = (size_t)bh * S_LEN * D_DIM;
    const float* qh = q + head_off;
    const float* kh = k + head_off;
    const float* vh = v + head_off;
    float*       oh = out + head_off;

    bf16x8 qf[2];
    {
        const int qrow = qbase + w * 16 + l15;
        const float* qp = qh + (size_t)qrow * D_DIM + 8 * lg;
#pragma unroll
        for (int c = 0; c < 2; ++c) {
            float4 a = *(const float4*)(qp + c * 32);
            float4 b = *(const float4*)(qp + c * 32 + 4);
            bf16x8 f;
            f[0] = (__bf16)(a.x * 0.125f); f[1] = (__bf16)(a.y * 0.125f);
            f[2] = (__bf16)(a.z * 0.125f); f[3] = (__bf16)(a.w * 0.125f);
            f[4] = (__bf16)(b.x * 0.125f); f[5] = (__bf16)(b.y * 0.125f);
            f[6] = (__bf16)(b.z * 0.125f); f[7] = (__bf16)(b.w * 0.125f);
            qf[c] = f;
        }
    }

    f32x4 acc[4] = {};
    float m_run[4], l_run[4];
#pragma unroll
    for (int r = 0; r < 4; ++r) { m_run[r] = -1e30f; l_run[r] = 0.0f; }

    const int nkv = qtile + 1;
    for (int kt = 0; kt < nkv; ++kt) {
        const int kv0 = kt * BKV;
        __syncthreads();
#pragma unroll
        for (int it = 0; it < 4; ++it) {
            int idx = tid + it * 256;
            int row = idx >> 4;
            int c4  = idx & 15;
            float4 kf = *(const float4*)(kh + (size_t)(kv0 + row) * D_DIM + c4 * 4);
            __bf16* kd = &Klds[row][c4 * 4];
            kd[0] = (__bf16)kf.x; kd[1] = (__bf16)kf.y;
            kd[2] = (__bf16)kf.z; kd[3] = (__bf16)kf.w;
            float4 vf = *(const float4*)(vh + (size_t)(kv0 + row) * D_DIM + c4 * 4);
            Vt[c4 * 4 + 0][row] = (__bf16)vf.x;
            Vt[c4 * 4 + 1][row] = (__bf16)vf.y;
            Vt[c4 * 4 + 2][row] = (__bf16)vf.z;
            Vt[c4 * 4 + 3][row] = (__bf16)vf.w;
        }
        __syncthreads();

        f32x4 sfrag[4];
#pragma unroll
        for (int kc = 0; kc < 4; ++kc) {
            bf16x8 kf0 = *(const bf16x8*)&Klds[kc * 16 + l15][8 * lg];
            bf16x8 kf1 = *(const bf16x8*)&Klds[kc * 16 + l15][32 + 8 * lg];
            f32x4 c = {};
            c = __builtin_amdgcn_mfma_f32_16x16x32_bf16(qf[0], kf0, c, 0, 0, 0);
            c = __builtin_amdgcn_mfma_f32_16x16x32_bf16(qf[1], kf1, c, 0, 0, 0);
            sfrag[kc] = c;
        }

        if (kt == qtile) {
#pragma unroll
            for (int kc = 0; kc < 4; ++kc) {
                const int j = kv0 + kc * 16 + l15;
#pragma unroll
                for (int r = 0; r < 4; ++r) {
                    const int qrow = qbase + w * 16 + lg * 4 + r;
                    if (j > qrow) sfrag[kc][r] = -1e30f;
                }
            }
        }

        float mt[4], corr[4], ps[4];
#pragma unroll
        for (int r = 0; r < 4; ++r) {
            float mx = fmaxf(fmaxf(sfrag[0][r], sfrag[1][r]),
                             fmaxf(sfrag[2][r], sfrag[3][r]));
            mx = fmaxf(mx, __shfl_xor(mx, 1));
            mx = fmaxf(mx, __shfl_xor(mx, 2));
            mx = fmaxf(mx, __shfl_xor(mx, 4));
            mx = fmaxf(mx, __shfl_xor(mx, 8));
            mt[r]   = fmaxf(m_run[r], mx);
            corr[r] = __expf(m_run[r] - mt[r]);
            ps[r]   = 0.0f;
        }
#pragma unroll
        for (int kc = 0; kc < 4; ++kc) {
#pragma unroll
            for (int r = 0; r < 4; ++r) {
                float pp = __expf(sfrag[kc][r] - mt[r]);
                ps[r] += pp;
                Plds[w][lg * 4 + r][kc * 16 + l15] = (__bf16)pp;
            }
        }
#pragma unroll
        for (int r = 0; r < 4; ++r) {
            ps[r] += __shfl_xor(ps[r], 1);
            ps[r] += __shfl_xor(ps[r], 2);
            ps[r] += __shfl_xor(ps[r], 4);
            ps[r] += __shfl_xor(ps[r], 8);
            l_run[r] = l_run[r] * corr[r] + ps[r];
            m_run[r] = mt[r];
        }
#pragma unroll
        for (int dt = 0; dt < 4; ++dt)
#pragma unroll
            for (int r = 0; r < 4; ++r)
                acc[dt][r] *= corr[r];

#pragma unroll
        for (int kk = 0; kk < 2; ++kk) {
            bf16x8 pf = *(const bf16x8*)&Plds[w][l15][kk * 32 + 8 * lg];
#pragma unroll
            for (int dt = 0; dt < 4; ++dt) {
                bf16x8 vf = *(const bf16x8*)&Vt[dt * 16 + l15][kk * 32 + 8 * lg];
                acc[dt] = __builtin_amdgcn_mfma_f32_16x16x32_bf16(pf, vf, acc[dt], 0, 0, 0);
            }
        }
    }

#pragma unroll
    for (int dt = 0; dt < 4; ++dt) {
#pragma unroll
        for (int r = 0; r < 4; ++r) {
            const int qrow = qbase + w * 16 + lg * 4 + r;
            oh[(size_t)qrow * D_DIM + dt * 16 + l15] = acc[dt][r] / l_run[r];
        }
    }
}

extern "C" void kernel_launch(void* const* d_in, const int* in_sizes, int n_in,
                              void* d_out, int out_size, void* d_ws, size_t ws_size,
                              hipStream_t stream) {
    const float* q = (const float*)d_in[0];
    const float* k = (const float*)d_in[1];
    const float* v = (const float*)d_in[2];
    float* out = (float*)d_out;

    const size_t kv_elems  = (size_t)NBH * S_LEN * D_DIM;       // 4,194,304
    const size_t ws_needed = kv_elems * 2 * sizeof(__bf16);     // 16 MiB

    if (ws_size >= ws_needed) {
        __bf16* kb = (__bf16*)d_ws;
        __bf16* vt = kb + kv_elems;
        conv_k_kernel<<<dim3(kv_elems / (256 * 8)), dim3(256), 0, stream>>>(k, kb);
        conv_vt_kernel<<<dim3(S_LEN / 64, NBH), dim3(256), 0, stream>>>(v, vt);
        attn_fwd_glds<<<dim3(NQT / 2, NBH), dim3(256), 0, stream>>>(q, kb, vt, out);
    } else {
        attn_fwd_fallback<<<dim3(NQT, NBH), dim3(256), 0, stream>>>(q, k, v, out);
    }
}

// Round 4
// 57.122 us; speedup vs baseline: 3.1051x; 1.1306x over previous
//
#include <hip/hip_runtime.h>
#include <hip/hip_bf16.h>

// Flash-attention forward, causal, B=2 H=16 S=2048 D=64, fp32 in/out.
// Round 4: no cross-lane ops in common softmax path (local-max + __any trigger,
// per-lane partial l reduced in epilogue), fused K/V convert kernel, rcp epilogue.
// Kept from r3: causal pairing, 3-buffer vmcnt(4) pipeline, XOR-swizzled LDS,
// permuted V^T columns (single ds_read_b128 B-fragments), setprio around MFMA.

#define S_LEN 2048
#define D_DIM 64
#define BQ 64
#define BKV 64
#define NQT (S_LEN / BQ)
#define NBH 32

typedef __bf16 bf16x8 __attribute__((ext_vector_type(8)));
typedef __bf16 bf16x4 __attribute__((ext_vector_type(4)));
typedef float f32x4 __attribute__((ext_vector_type(4)));

#define QSCALE 0.1803368801111243f   // (1/8) * log2(e)
#define NEG_INF (-1e30f)
#define THRLOG2 11.5f                // defer-max threshold (log2 domain) ~ e^8

__device__ inline void glds16(const void* g, void* l) {
    __builtin_amdgcn_global_load_lds(
        (const __attribute__((address_space(1))) unsigned int*)g,
        (__attribute__((address_space(3))) unsigned int*)l, 16, 0, 0);
}

__device__ inline float m3(float a, float b, float c) {
    return fmaxf(fmaxf(a, b), c);    // clang fuses to v_max3_f32
}

// ---------------- fused convert kernel ----------------
// K: straight fp32->bf16. V: transposed to [bh][d][s] with per-64-col-block
// permutation: dest col c=(kk<<5)|(g<<3)|(b<<2)|i0 holds src j=(kk<<5)|(b<<4)|(g<<2)|i0
// so the PV B-fragment is one contiguous 16B read.
__global__ __launch_bounds__(256)
void conv_fused_kernel(const float* __restrict__ k, const float* __restrict__ v,
                       __bf16* __restrict__ kb, __bf16* __restrict__ vt)
{
    __shared__ __bf16 T[64][72];
    const int bh = blockIdx.y, st = blockIdx.x;
    const int tid = threadIdx.x;
    const size_t base = (size_t)bh * S_LEN * D_DIM + (size_t)st * 64 * D_DIM;
    const float* kh = k + base;
    const float* vh = v + base;
    __bf16* kbh = kb + base;

    // K pass: 64x64 elems, 8 per thread per iter, 2 iters
#pragma unroll
    for (int it = 0; it < 2; ++it) {
        size_t i = ((size_t)tid + it * 256) * 8;
        float4 a = *(const float4*)(kh + i);
        float4 b = *(const float4*)(kh + i + 4);
        bf16x8 o;
        o[0] = (__bf16)a.x; o[1] = (__bf16)a.y; o[2] = (__bf16)a.z; o[3] = (__bf16)a.w;
        o[4] = (__bf16)b.x; o[5] = (__bf16)b.y; o[6] = (__bf16)b.z; o[7] = (__bf16)b.w;
        *(bf16x8*)(kbh + i) = o;
    }

    // V pass: stage into LDS transposed
#pragma unroll
    for (int it = 0; it < 4; ++it) {
        int idx = tid + it * 256;          // 64 s-rows x 16 float4
        int s = idx >> 4, c4 = idx & 15;
        float4 f = *(const float4*)(vh + s * D_DIM + c4 * 4);
        T[c4 * 4 + 0][s] = (__bf16)f.x;
        T[c4 * 4 + 1][s] = (__bf16)f.y;
        T[c4 * 4 + 2][s] = (__bf16)f.z;
        T[c4 * 4 + 3][s] = (__bf16)f.w;
    }
    __syncthreads();
    __bf16* vth = vt + (size_t)bh * D_DIM * S_LEN + st * 64;
#pragma unroll
    for (int it = 0; it < 2; ++it) {
        int idx = tid + it * 256;          // 64 d-rows x 8 chunks of 8
        int d = idx >> 3, c8 = idx & 7;
        int kk = c8 >> 2, g = c8 & 3;
        bf16x4 v0 = *(const bf16x4*)&T[d][kk * 32 + 4 * g];        // b=0
        bf16x4 v1 = *(const bf16x4*)&T[d][kk * 32 + 16 + 4 * g];   // b=1
        bf16x8 o;
        o[0] = v0[0]; o[1] = v0[1]; o[2] = v0[2]; o[3] = v0[3];
        o[4] = v1[0]; o[5] = v1[1]; o[6] = v1[2]; o[7] = v1[3];
        *(bf16x8*)(vth + (size_t)d * S_LEN + c8 * 8) = o;
    }
}

// ---------------- attention kernel ----------------

__global__ __launch_bounds__(256)
void attn_fwd_glds(const float* __restrict__ q, const __bf16* __restrict__ kb,
                   const __bf16* __restrict__ vt, float* __restrict__ out)
{
    __shared__ __bf16 KL[3][64][64];   // [buf][j][d], cols XOR-swizzled by ((j&7)<<3)
    __shared__ __bf16 VL[3][64][64];   // [buf][d][c], permuted cols, XOR-swizzled by ((d&7)<<3)

    const int tid  = threadIdx.x;
    const int w    = tid >> 6;
    const int lane = tid & 63;
    const int l15  = lane & 15;
    const int lg   = lane >> 4;

    const int p  = blockIdx.x;         // pair index 0..15
    const int bh = blockIdx.y;

    const float*  qh = q  + (size_t)bh * S_LEN * D_DIM;
    const __bf16* kh = kb + (size_t)bh * S_LEN * D_DIM;
    const __bf16* vh = vt + (size_t)bh * D_DIM * S_LEN;
    float*        oh = out + (size_t)bh * S_LEN * D_DIM;

    // staging decode (chunk c = u*4 + w; LDS elems e = c*512 + lane*8)
    int row_u[2], scol_u[2];
#pragma unroll
    for (int u = 0; u < 2; ++u) {
        int e = (u * 4 + w) * 512 + lane * 8;
        int r = e >> 6, c0 = e & 63;
        row_u[u]  = r;
        scol_u[u] = c0 ^ ((r & 7) << 3);
    }

#define STAGE(kt, buf)                                                          \
    {                                                                           \
        _Pragma("unroll")                                                       \
        for (int u = 0; u < 2; ++u) {                                           \
            glds16(kh + (size_t)((kt) * BKV + row_u[u]) * D_DIM + scol_u[u],    \
                   (__bf16*)&KL[buf][0][0] + (u * 4 + w) * 512);                \
            glds16(vh + (size_t)row_u[u] * S_LEN + (kt) * BKV + scol_u[u],      \
                   (__bf16*)&VL[buf][0][0] + (u * 4 + w) * 512);                \
        }                                                                       \
    }

    for (int half = 0; half < 2; ++half) {
        const int qtile = (half == 0) ? (NQT - 1 - p) : p;   // big half first
        const int qbase = qtile * BQ;
        const int nt    = qtile + 1;

        // ---- Q fragment (B operand): l15 = q row, elems d = kk*32 + 8*lg + i
        bf16x8 qf[2];
        {
            const int qrow = qbase + w * 16 + l15;
            const float* qp = qh + (size_t)qrow * D_DIM + 8 * lg;
#pragma unroll
            for (int kk = 0; kk < 2; ++kk) {
                float4 a = *(const float4*)(qp + kk * 32);
                float4 b = *(const float4*)(qp + kk * 32 + 4);
                bf16x8 f;
                f[0] = (__bf16)(a.x * QSCALE); f[1] = (__bf16)(a.y * QSCALE);
                f[2] = (__bf16)(a.z * QSCALE); f[3] = (__bf16)(a.w * QSCALE);
                f[4] = (__bf16)(b.x * QSCALE); f[5] = (__bf16)(b.y * QSCALE);
                f[6] = (__bf16)(b.z * QSCALE); f[7] = (__bf16)(b.w * QSCALE);
                qf[kk] = f;
            }
        }

        f32x4 acc[4] = {};
        float m_run = NEG_INF;     // synced across the 4 lane-copies of each q
        float l_part = 0.0f;       // per-lane partial row-sum (reduced in epilogue)

        if (half == 1) __syncthreads();   // protect LDS reuse across halves
        STAGE(0, 0);
        if (nt > 1) STAGE(1, 1);

        for (int kt = 0; kt < nt; ++kt) {
            const int cur = kt % 3;
            if (kt + 1 < nt) { asm volatile("s_waitcnt vmcnt(4)" ::: "memory"); }
            else             { asm volatile("s_waitcnt vmcnt(0)" ::: "memory"); }
            __builtin_amdgcn_s_barrier();
            if (kt + 2 < nt) STAGE(kt + 2, (kt + 2) % 3);

            // ---- swapped QK^T: s = mfma(K, Q); lane holds S[j][q=l15], j = jt*16+4lg+r
            f32x4 s[4];
            __builtin_amdgcn_s_setprio(1);
#pragma unroll
            for (int jt = 0; jt < 4; ++jt) {
                const int j  = jt * 16 + l15;
                const int sw = (j & 7) << 3;
                f32x4 c = {};
#pragma unroll
                for (int kk = 0; kk < 2; ++kk) {
                    bf16x8 kf = *(const bf16x8*)&KL[cur][j][(kk * 32 + 8 * lg) ^ sw];
                    c = __builtin_amdgcn_mfma_f32_16x16x32_bf16(kf, qf[kk], c, 0, 0, 0);
                }
                s[jt] = c;
            }
            __builtin_amdgcn_s_setprio(0);

            // ---- causal mask on diagonal tile
            if (kt == qtile) {
                const int qin = w * 16 + l15;
#pragma unroll
                for (int jt = 0; jt < 4; ++jt)
#pragma unroll
                    for (int r = 0; r < 4; ++r)
                        if (jt * 16 + 4 * lg + r > qin) s[jt][r] = NEG_INF;
            }

            // ---- local row max (this lane's 16 scores; no cross-lane in common path)
            float t0 = m3(s[0][0], s[0][1], s[0][2]);
            float t1 = m3(s[0][3], s[1][0], s[1][1]);
            float t2 = m3(s[1][2], s[1][3], s[2][0]);
            float t3 = m3(s[2][1], s[2][2], s[2][3]);
            float t4 = m3(s[3][0], s[3][1], s[3][2]);
            float mxl = m3(m3(t0, t1, t2), m3(t3, t4, s[3][3]), NEG_INF);

            // ---- defer-max: cross-lane reduce + rescale only when max grew materially
            if (__any(mxl > m_run + THRLOG2)) {
                float mx = fmaxf(mxl, __shfl_xor(mxl, 16));
                mx = fmaxf(mx, __shfl_xor(mx, 32));
                const float mt   = fmaxf(m_run, mx);
                const float corr = __builtin_amdgcn_exp2f(m_run - mt);
                l_part *= corr;
                m_run   = mt;
                float corr_a[4];
#pragma unroll
                for (int r = 0; r < 4; ++r) corr_a[r] = __shfl(corr, 4 * lg + r);
#pragma unroll
                for (int dt = 0; dt < 4; ++dt)
#pragma unroll
                    for (int r = 0; r < 4; ++r) acc[dt][r] *= corr_a[r];
            }

            // ---- P = exp2(s - m), per-lane partial sum, bf16 A-fragments
            float ps = 0.0f;
            float pe[4][4];
#pragma unroll
            for (int jt = 0; jt < 4; ++jt)
#pragma unroll
                for (int r = 0; r < 4; ++r) {
                    float e = __builtin_amdgcn_exp2f(s[jt][r] - m_run);
                    pe[jt][r] = e;
                    ps += e;
                }
            l_part += ps;

            bf16x8 pa[2];
#pragma unroll
            for (int kk = 0; kk < 2; ++kk)
#pragma unroll
                for (int i = 0; i < 4; ++i) {
                    pa[kk][i]     = (__bf16)pe[2 * kk][i];
                    pa[kk][4 + i] = (__bf16)pe[2 * kk + 1][i];
                }

            // ---- PV: single b128 B-fragment thanks to permuted V^T columns
            __builtin_amdgcn_s_setprio(1);
#pragma unroll
            for (int dt = 0; dt < 4; ++dt) {
                const int d  = dt * 16 + l15;
                const int sw = (d & 7) << 3;
#pragma unroll
                for (int kk = 0; kk < 2; ++kk) {
                    bf16x8 vb = *(const bf16x8*)&VL[cur][d][(kk * 32 + 8 * lg) ^ sw];
                    acc[dt] = __builtin_amdgcn_mfma_f32_16x16x32_bf16(pa[kk], vb, acc[dt], 0, 0, 0);
                }
            }
            __builtin_amdgcn_s_setprio(0);
        }

        // ---- epilogue: reduce l across the 4 lane-copies, then write O = acc/l
        float l_tot = l_part + __shfl_xor(l_part, 16);
        l_tot += __shfl_xor(l_tot, 32);
        float li_a[4];
#pragma unroll
        for (int r = 0; r < 4; ++r)
            li_a[r] = __builtin_amdgcn_rcpf(__shfl(l_tot, 4 * lg + r));
#pragma unroll
        for (int dt = 0; dt < 4; ++dt)
#pragma unroll
            for (int r = 0; r < 4; ++r)
                oh[(size_t)(qbase + w * 16 + 4 * lg + r) * D_DIM + dt * 16 + l15] =
                    acc[dt][r] * li_a[r];
    }
#undef STAGE
}

// ---------------- fallback (no-ws path) ----------------

#define PAD 72
__global__ __launch_bounds__(256)
void attn_fwd_fallback(const float* __restrict__ q, const float* __restrict__ k,
                       const float* __restrict__ v, float* __restrict__ out)
{
    __shared__ __bf16 Klds[BKV][PAD];
    __shared__ __bf16 Vt[D_DIM][PAD];
    __shared__ __bf16 Plds[4][16][PAD];

    const int tid  = threadIdx.x;
    const int w    = tid >> 6;
    const int lane = tid & 63;
    const int l15  = lane & 15;
    const int lg   = lane >> 4;

    const int qtile = blockIdx.x;
    const int bh    = blockIdx.y;
    const int qbase = qtile * BQ;

    const size_t head_off = (size_t)bh * S_LEN * D_DIM;
    const float* qh = q + head_off;
    const float* kh = k + head_off;
    const float* vh = v + head_off;
    float*       oh = out + head_off;

    bf16x8 qf[2];
    {
        const int qrow = qbase + w * 16 + l15;
        const float* qp = qh + (size_t)qrow * D_DIM + 8 * lg;
#pragma unroll
        for (int c = 0; c < 2; ++c) {
            float4 a = *(const float4*)(qp + c * 32);
            float4 b = *(const float4*)(qp + c * 32 + 4);
            bf16x8 f;
            f[0] = (__bf16)(a.x * 0.125f); f[1] = (__bf16)(a.y * 0.125f);
            f[2] = (__bf16)(a.z * 0.125f); f[3] = (__bf16)(a.w * 0.125f);
            f[4] = (__bf16)(b.x * 0.125f); f[5] = (__bf16)(b.y * 0.125f);
            f[6] = (__bf16)(b.z * 0.125f); f[7] = (__bf16)(b.w * 0.125f);
            qf[c] = f;
        }
    }

    f32x4 acc[4] = {};
    float m_run[4], l_run[4];
#pragma unroll
    for (int r = 0; r < 4; ++r) { m_run[r] = -1e30f; l_run[r] = 0.0f; }

    const int nkv = qtile + 1;
    for (int kt = 0; kt < nkv; ++kt) {
        const int kv0 = kt * BKV;
        __syncthreads();
#pragma unroll
        for (int it = 0; it < 4; ++it) {
            int idx = tid + it * 256;
            int row = idx >> 4;
            int c4  = idx & 15;
            float4 kf = *(const float4*)(kh + (size_t)(kv0 + row) * D_DIM + c4 * 4);
            __bf16* kd = &Klds[row][c4 * 4];
            kd[0] = (__bf16)kf.x; kd[1] = (__bf16)kf.y;
            kd[2] = (__bf16)kf.z; kd[3] = (__bf16)kf.w;
            float4 vf = *(const float4*)(vh + (size_t)(kv0 + row) * D_DIM + c4 * 4);
            Vt[c4 * 4 + 0][row] = (__bf16)vf.x;
            Vt[c4 * 4 + 1][row] = (__bf16)vf.y;
            Vt[c4 * 4 + 2][row] = (__bf16)vf.z;
            Vt[c4 * 4 + 3][row] = (__bf16)vf.w;
        }
        __syncthreads();

        f32x4 sfrag[4];
#pragma unroll
        for (int kc = 0; kc < 4; ++kc) {
            bf16x8 kf0 = *(const bf16x8*)&Klds[kc * 16 + l15][8 * lg];
            bf16x8 kf1 = *(const bf16x8*)&Klds[kc * 16 + l15][32 + 8 * lg];
            f32x4 c = {};
            c = __builtin_amdgcn_mfma_f32_16x16x32_bf16(qf[0], kf0, c, 0, 0, 0);
            c = __builtin_amdgcn_mfma_f32_16x16x32_bf16(qf[1], kf1, c, 0, 0, 0);
            sfrag[kc] = c;
        }

        if (kt == qtile) {
#pragma unroll
            for (int kc = 0; kc < 4; ++kc) {
                const int j = kv0 + kc * 16 + l15;
#pragma unroll
                for (int r = 0; r < 4; ++r) {
                    const int qrow = qbase + w * 16 + lg * 4 + r;
                    if (j > qrow) sfrag[kc][r] = -1e30f;
                }
            }
        }

        float mt[4], corr[4], ps[4];
#pragma unroll
        for (int r = 0; r < 4; ++r) {
            float mx = fmaxf(fmaxf(sfrag[0][r], sfrag[1][r]),
                             fmaxf(sfrag[2][r], sfrag[3][r]));
            mx = fmaxf(mx, __shfl_xor(mx, 1));
            mx = fmaxf(mx, __shfl_xor(mx, 2));
            mx = fmaxf(mx, __shfl_xor(mx, 4));
            mx = fmaxf(mx, __shfl_xor(mx, 8));
            mt[r]   = fmaxf(m_run[r], mx);
            corr[r] = __expf(m_run[r] - mt[r]);
            ps[r]   = 0.0f;
        }
#pragma unroll
        for (int kc = 0; kc < 4; ++kc) {
#pragma unroll
            for (int r = 0; r < 4; ++r) {
                float pp = __expf(sfrag[kc][r] - mt[r]);
                ps[r] += pp;
                Plds[w][lg * 4 + r][kc * 16 + l15] = (__bf16)pp;
            }
        }
#pragma unroll
        for (int r = 0; r < 4; ++r) {
            ps[r] += __shfl_xor(ps[r], 1);
            ps[r] += __shfl_xor(ps[r], 2);
            ps[r] += __shfl_xor(ps[r], 4);
            ps[r] += __shfl_xor(ps[r], 8);
            l_run[r] = l_run[r] * corr[r] + ps[r];
            m_run[r] = mt[r];
        }
#pragma unroll
        for (int dt = 0; dt < 4; ++dt)
#pragma unroll
            for (int r = 0; r < 4; ++r)
                acc[dt][r] *= corr[r];

#pragma unroll
        for (int kk = 0; kk < 2; ++kk) {
            bf16x8 pf = *(const bf16x8*)&Plds[w][l15][kk * 32 + 8 * lg];
#pragma unroll
            for (int dt = 0; dt < 4; ++dt) {
                bf16x8 vf = *(const bf16x8*)&Vt[dt * 16 + l15][kk * 32 + 8 * lg];
                acc[dt] = __builtin_amdgcn_mfma_f32_16x16x32_bf16(pf, vf, acc[dt], 0, 0, 0);
            }
        }
    }

#pragma unroll
    for (int dt = 0; dt < 4; ++dt) {
#pragma unroll
        for (int r = 0; r < 4; ++r) {
            const int qrow = qbase + w * 16 + lg * 4 + r;
            oh[(size_t)qrow * D_DIM + dt * 16 + l15] = acc[dt][r] / l_run[r];
        }
    }
}

extern "C" void kernel_launch(void* const* d_in, const int* in_sizes, int n_in,
                              void* d_out, int out_size, void* d_ws, size_t ws_size,
                              hipStream_t stream) {
    const float* q = (const float*)d_in[0];
    const float* k = (const float*)d_in[1];
    const float* v = (const float*)d_in[2];
    float* out = (float*)d_out;

    const size_t kv_elems  = (size_t)NBH * S_LEN * D_DIM;       // 4,194,304
    const size_t ws_needed = kv_elems * 2 * sizeof(__bf16);     // 16 MiB

    if (ws_size >= ws_needed) {
        __bf16* kb = (__bf16*)d_ws;
        __bf16* vt = kb + kv_elems;
        conv_fused_kernel<<<dim3(S_LEN / 64, NBH), dim3(256), 0, stream>>>(k, v, kb, vt);
        attn_fwd_glds<<<dim3(NQT / 2, NBH), dim3(256), 0, stream>>>(q, kb, vt, out);
    } else {
        attn_fwd_fallback<<<dim3(NQT, NBH), dim3(256), 0, stream>>>(q, k, v, out);
    }
}